// Round 12
// baseline (139.203 us; speedup 1.0000x reference)
//
#include <hip/hip_runtime.h>
#include <cstdint>
#include <cstddef>

#define B_ 2048
#define IN_ 8192
#define O_ 4096
#define K_ 64
#define BP_ (B_ / 2)  // 1024 bf16-pair dwords per xT row

typedef float vfloat4 __attribute__((ext_vector_type(4)));  // clang-native for nt-store

// bf16 pair helpers: low 16 bits = even b, high 16 bits = odd b
__device__ __forceinline__ float blo(uint32_t p) { return __uint_as_float(p << 16); }
__device__ __forceinline__ float bhi(uint32_t p) { return __uint_as_float(p & 0xffff0000u); }

// ---------------------------------------------------------------------------
// Kernel 1: transpose + bf16-pack  x[B][IN] f32  ->  xT[IN][BP] u32 (bf16x2)
// ---------------------------------------------------------------------------
__global__ __launch_bounds__(256) void xpose_pack(const float* __restrict__ x,
                                                  uint32_t* __restrict__ xT) {
    __shared__ uint16_t T[64][65];  // 64 i x 64 b tile, +1 pad
    const int t  = threadIdx.x;
    const int b0 = blockIdx.x << 6;   // 32 tiles over B
    const int i0 = blockIdx.y << 6;   // 128 tiles over IN
    const int il = t & 63;
    const int bq = t >> 6;            // 0..3
#pragma unroll
    for (int r = 0; r < 16; ++r) {
        int bl = (bq << 4) + r;
        float v = x[(size_t)(b0 + bl) * IN_ + i0 + il];  // coalesced over il
        uint32_t u = __float_as_uint(v);
        u += 0x7fffu + ((u >> 16) & 1u);                  // round-to-nearest-even
        T[il][bl] = (uint16_t)(u >> 16);
    }
    __syncthreads();
#pragma unroll
    for (int r = 0; r < 8; ++r) {
        int flat = t + (r << 8);
        int iw = flat >> 5;   // 0..63
        int bp = flat & 31;   // 0..31
        uint32_t lo = T[iw][2 * bp];
        uint32_t hi = T[iw][2 * bp + 1];
        __builtin_nontemporal_store(lo | (hi << 16),
                                    &xT[(size_t)(i0 + iw) * BP_ + (b0 >> 1) + bp]);
    }
}

// ---------------------------------------------------------------------------
// Kernel 2: main. Block = 256 threads = 4 waves. Block tile: 256 b x 16 o.
// XCD-aligned: b-tile = f&7 pins each 4 MB xT column slice to one XCD's L2.
// Lane-split dwordx4 gathers: one wave-load = TWO rows' 512B chunks
// (lanes 0-31 -> r0, lanes 32-63 -> r1, 16B/lane).
// KEY CHANGE vs R9 (one variable): batch depth 8 -> 16 loads in flight
// (kb loop 4 -> 2 iterations). Occupancy tier unchanged ((256,4), VGPR
// budget 128, est ~100): isolates MLP depth vs request-capacity wall.
// ---------------------------------------------------------------------------
__global__ __launch_bounds__(256, 4) void spl_main(const uint32_t* __restrict__ xT,
                                                   const int* __restrict__ idx,
                                                   const float* __restrict__ w,
                                                   const float* __restrict__ bias,
                                                   float* __restrict__ out) {
    __shared__ float tile[256][17];  // [b_local][o_local], 17.4 KB
    const int t     = threadIdx.x;
    const int lane  = t & 63;
    const int half  = lane >> 5;        // 0: even-slot rows, 1: odd-slot rows
    const int l5    = lane & 31;
    const int f     = blockIdx.x;
    const int btile = f & 7;            // == XCD id under round-robin dispatch
    const int otile = f >> 3;           // 0..255
    const int obase = otile << 4;
    const int bbase = btile << 8;
    const int cbase = bbase >> 1;       // chunk dword base (scalar)
    const int wv    = __builtin_amdgcn_readfirstlane(t >> 6);  // force scalar o

    for (int oi = 0; oi < 4; ++oi) {
        const int o = obase + (wv << 2) + oi;            // uniform per wave
        const int*   ip = idx + o * K_;                  // -> s_load
        const float* wp = w + o * K_;                    // -> s_load
        float a0 = 0.f, a1 = 0.f, a2 = 0.f, a3 = 0.f;
        float a4 = 0.f, a5 = 0.f, a6 = 0.f, a7 = 0.f;
#pragma unroll
        for (int kb = 0; kb < 2; ++kb) {
            // ---- issue 16 dwordx4 gathers covering 32 rows ----
            uint4 q[16];
            float ws[16];
#pragma unroll
            for (int j = 0; j < 16; ++j) {
                int k2 = (kb << 5) + 2 * j;
                int r0 = ip[k2];                         // wave-uniform (scalar)
                int r1 = ip[k2 + 1];
                const uint32_t* p0 = xT + ((size_t)r0 << 10) + cbase;
                const uint32_t* p1 = xT + ((size_t)r1 << 10) + cbase;
                const uint32_t* ps = half ? p1 : p0;     // v_cndmask on base
                q[j]  = *(const uint4*)(ps + (l5 << 2)); // 16B/lane, 1024B/wave
                ws[j] = half ? wp[k2 + 1] : wp[k2];
            }
            __builtin_amdgcn_sched_barrier(0);  // no FMA hoisted above the loads
            // ---- consume in issue order (progressive vmcnt drain) ----
#pragma unroll
            for (int j = 0; j < 16; ++j) {
                float wj = ws[j];
                a0 = fmaf(blo(q[j].x), wj, a0);
                a1 = fmaf(bhi(q[j].x), wj, a1);
                a2 = fmaf(blo(q[j].y), wj, a2);
                a3 = fmaf(bhi(q[j].y), wj, a3);
                a4 = fmaf(blo(q[j].z), wj, a4);
                a5 = fmaf(bhi(q[j].z), wj, a5);
                a6 = fmaf(blo(q[j].w), wj, a6);
                a7 = fmaf(bhi(q[j].w), wj, a7);
            }
        }
        // combine even-row half (lanes 0-31) with odd-row half (lanes 32-63);
        // lane l5 owns b = bbase + 8*l5 .. 8*l5+7
        const float bo = bias[o];
        const int ol = (wv << 2) + oi;
        float s0 = a0 + __shfl_xor(a0, 32, 64);
        float s1 = a1 + __shfl_xor(a1, 32, 64);
        float s2 = a2 + __shfl_xor(a2, 32, 64);
        float s3 = a3 + __shfl_xor(a3, 32, 64);
        float s4 = a4 + __shfl_xor(a4, 32, 64);
        float s5 = a5 + __shfl_xor(a5, 32, 64);
        float s6 = a6 + __shfl_xor(a6, 32, 64);
        float s7 = a7 + __shfl_xor(a7, 32, 64);
        if (half == 0) {
            const int bl0 = l5 << 3;
            tile[bl0 + 0][ol] = s0 + bo;
            tile[bl0 + 1][ol] = s1 + bo;
            tile[bl0 + 2][ol] = s2 + bo;
            tile[bl0 + 3][ol] = s3 + bo;
            tile[bl0 + 4][ol] = s4 + bo;
            tile[bl0 + 5][ol] = s5 + bo;
            tile[bl0 + 6][ol] = s6 + bo;
            tile[bl0 + 7][ol] = s7 + bo;
        }
    }
    __syncthreads();
    // coalesced store: 256 b x 16 o; 4 float4 per thread
    const int bl_ = t >> 2;         // 0..63
    const int ol4 = (t & 3) << 2;   // 0,4,8,12
#pragma unroll
    for (int r = 0; r < 4; ++r) {
        int bl = bl_ + (r << 6);
        vfloat4 v;
        v.x = tile[bl][ol4 + 0];
        v.y = tile[bl][ol4 + 1];
        v.z = tile[bl][ol4 + 2];
        v.w = tile[bl][ol4 + 3];
        __builtin_nontemporal_store(v,
            (vfloat4*)&out[(size_t)(bbase + bl) * O_ + obase + ol4]);
    }
}

// ---------------------------------------------------------------------------
// Fallback (only if workspace is unexpectedly small): correct but slow.
// ---------------------------------------------------------------------------
__global__ __launch_bounds__(256) void spl_naive(const float* __restrict__ x,
                                                 const int* __restrict__ idx,
                                                 const float* __restrict__ w,
                                                 const float* __restrict__ bias,
                                                 float* __restrict__ out) {
    int o = blockIdx.x * 256 + threadIdx.x;
    int b = blockIdx.y;
    const float* xr = x + (size_t)b * IN_;
    float acc = bias[o];
    for (int k = 0; k < K_; ++k)
        acc = fmaf(xr[idx[o * K_ + k]], w[o * K_ + k], acc);
    out[(size_t)b * O_ + o] = acc;
}

extern "C" void kernel_launch(void* const* d_in, const int* in_sizes, int n_in,
                              void* d_out, int out_size, void* d_ws, size_t ws_size,
                              hipStream_t stream) {
    const float* x    = (const float*)d_in[0];
    const int*   idx  = (const int*)d_in[1];
    const float* w    = (const float*)d_in[2];
    const float* bias = (const float*)d_in[3];
    float*       out  = (float*)d_out;

    const size_t xt_bytes = (size_t)IN_ * BP_ * sizeof(uint32_t);  // 32 MiB
    if (ws_size >= xt_bytes) {
        uint32_t* xT = (uint32_t*)d_ws;
        hipLaunchKernelGGL(xpose_pack, dim3(B_ / 64, IN_ / 64), dim3(256), 0, stream, x, xT);
        hipLaunchKernelGGL(spl_main, dim3((O_ / 16) * (B_ / 256)), dim3(256), 0, stream,
                           xT, idx, w, bias, out);
    } else {
        hipLaunchKernelGGL(spl_naive, dim3(O_ / 256, B_), dim3(256), 0, stream,
                           x, idx, w, bias, out);
    }
}

// Round 13
// 86.654 us; speedup vs baseline: 1.6064x; 1.6064x over previous
//
#include <hip/hip_runtime.h>
#include <cstdint>
#include <cstddef>

#define B_ 2048
#define IN_ 8192
#define O_ 4096
#define K_ 64
#define BP_ (B_ / 2)  // 1024 bf16-pair dwords per xT row

typedef float vfloat4 __attribute__((ext_vector_type(4)));    // clang-native for nt-store
typedef uint32_t v2u  __attribute__((ext_vector_type(2)));    // ds_read_b64 payload

// bf16 pair helpers: low 16 bits = even b, high 16 bits = odd b
__device__ __forceinline__ float blo(uint32_t p) { return __uint_as_float(p << 16); }
__device__ __forceinline__ float bhi(uint32_t p) { return __uint_as_float(p & 0xffff0000u); }

// global -> LDS DMA, 16B per lane (dest = base + lane*16, wave-uniform base)
__device__ __forceinline__ void stage16(const uint32_t* g, uint32_t* l) {
    __builtin_amdgcn_global_load_lds(
        (const __attribute__((address_space(1))) void*)g,
        (__attribute__((address_space(3))) void*)l, 16, 0, 0);
}

// inline-asm ds_read_b64 with literal offset; manual lgkmcnt + sched_barrier
// later (rule #18). Keeps the LDS-DMA consume invisible to the compiler's
// waitcnt legalizer so it can't insert an auto vmcnt(0) drain.
#define DSR(dst, OFF) asm volatile("ds_read_b64 %0, %1 offset:" #OFF \
                                   : "=v"(dst) : "v"(va))

// ---------------------------------------------------------------------------
// Kernel 1: transpose + bf16-pack  x[B][IN] f32  ->  xT[IN][BP] u32 (bf16x2)
// ---------------------------------------------------------------------------
__global__ __launch_bounds__(256) void xpose_pack(const float* __restrict__ x,
                                                  uint32_t* __restrict__ xT) {
    __shared__ uint16_t T[64][65];  // 64 i x 64 b tile, +1 pad
    const int t  = threadIdx.x;
    const int b0 = blockIdx.x << 6;   // 32 tiles over B
    const int i0 = blockIdx.y << 6;   // 128 tiles over IN
    const int il = t & 63;
    const int bq = t >> 6;            // 0..3
#pragma unroll
    for (int r = 0; r < 16; ++r) {
        int bl = (bq << 4) + r;
        float v = x[(size_t)(b0 + bl) * IN_ + i0 + il];  // coalesced over il
        uint32_t u = __float_as_uint(v);
        u += 0x7fffu + ((u >> 16) & 1u);                  // round-to-nearest-even
        T[il][bl] = (uint16_t)(u >> 16);
    }
    __syncthreads();
#pragma unroll
    for (int r = 0; r < 8; ++r) {
        int flat = t + (r << 8);
        int iw = flat >> 5;   // 0..63
        int bp = flat & 31;   // 0..31
        uint32_t lo = T[iw][2 * bp];
        uint32_t hi = T[iw][2 * bp + 1];
        __builtin_nontemporal_store(lo | (hi << 16),
                                    &xT[(size_t)(i0 + iw) * BP_ + (b0 >> 1) + bp]);
    }
}

// ---------------------------------------------------------------------------
// Kernel 2: main. Block = 256 threads = 4 waves. Block tile: 256 b x 16 o.
// XCD-aligned: b-tile = f&7 pins each 4 MB xT column slice to one XCD's L2.
// KEY CHANGE vs R9/R12: gathers go through global_load_lds DMA into a
// per-wave 8KB LDS staging buffer (2 halves x 8 rows x 512B), software-
// pipelined with counted s_waitcnt vmcnt(4) (never 0 mid-loop). Data never
// touches VGPRs in flight -> no spill ceiling on MLP; tests whether the
// ~26 B/cyc/CU wall is TCP-MSHR tracking (bypassed by DMA) or fabric.
// Consume via inline-asm ds_read_b64 + manual lgkmcnt(0)+sched_barrier.
// ---------------------------------------------------------------------------
__global__ __launch_bounds__(256, 4) void spl_main(const uint32_t* __restrict__ xT,
                                                   const int* __restrict__ idx,
                                                   const float* __restrict__ w,
                                                   const float* __restrict__ bias,
                                                   float* __restrict__ out) {
    __shared__ float tile[256][17];       // [b_local][o_local], 17.4 KB
    __shared__ uint32_t stage[4][2048];   // 4 waves x 8KB staging
    const int t     = threadIdx.x;
    const int lane  = t & 63;
    const int half  = lane >> 5;          // source row select within a DMA
    const int l5    = lane & 31;
    const int f     = blockIdx.x;
    const int btile = f & 7;              // == XCD id under round-robin dispatch
    const int otile = f >> 3;             // 0..255
    const int obase = otile << 4;
    const int bbase = btile << 8;
    const int cbase = bbase >> 1;         // chunk dword base (scalar)
    const int wv    = __builtin_amdgcn_readfirstlane(t >> 6);
    uint32_t* const sw = &stage[wv][0];   // wave-uniform staging base

    // LDS byte address for this thread's ds_read: base + lane*8 (loop-invariant)
    typedef __attribute__((address_space(3))) uint32_t lds_u32;
    const uint32_t va = (uint32_t)(size_t)(lds_u32*)sw + ((uint32_t)lane << 3);

    for (int oi = 0; oi < 4; ++oi) {
        const int o = obase + (wv << 2) + oi;            // uniform per wave
        const int*   ip = idx + o * K_;                  // -> s_load
        const float* wp = w + o * K_;                    // -> s_load
        float a0 = 0.f, a1 = 0.f, a2 = 0.f, a3 = 0.f;

        // prologue: batch 0 (rows 0..7) -> half 0
#pragma unroll
        for (int j = 0; j < 4; ++j) {
            int r0 = ip[2 * j];
            int r1 = ip[2 * j + 1];
            const uint32_t* src = xT + ((size_t)(half ? r1 : r0) << 10)
                                     + cbase + (l5 << 2);
            stage16(src, sw + j * 256);   // instr j -> slots 2j,2j+1
        }
#pragma unroll
        for (int tb = 0; tb < 8; ++tb) {
            if (tb < 7) {
                const int nb = tb + 1;
                uint32_t* dst = sw + (nb & 1) * 1024;
#pragma unroll
                for (int j = 0; j < 4; ++j) {
                    int k2 = (nb << 3) + 2 * j;
                    int r0 = ip[k2];
                    int r1 = ip[k2 + 1];
                    const uint32_t* src = xT + ((size_t)(half ? r1 : r0) << 10)
                                             + cbase + (l5 << 2);
                    stage16(src, dst + j * 256);
                }
                asm volatile("s_waitcnt vmcnt(4)" ::: "memory");  // batch tb landed
            } else {
                asm volatile("s_waitcnt vmcnt(0)" ::: "memory");  // final drain
            }
            __builtin_amdgcn_sched_barrier(0);
            // ---- consume batch tb from half (tb&1): 8 rows ----
            v2u q0, q1, q2, q3, q4, q5, q6, q7;
            if ((tb & 1) == 0) {
                DSR(q0, 0);    DSR(q1, 512);  DSR(q2, 1024); DSR(q3, 1536);
                DSR(q4, 2048); DSR(q5, 2560); DSR(q6, 3072); DSR(q7, 3584);
            } else {
                DSR(q0, 4096); DSR(q1, 4608); DSR(q2, 5120); DSR(q3, 5632);
                DSR(q4, 6144); DSR(q5, 6656); DSR(q6, 7168); DSR(q7, 7680);
            }
            asm volatile("s_waitcnt lgkmcnt(0)" ::: "memory");
            __builtin_amdgcn_sched_barrier(0);
#define CONS(Q, S)                                                  \
            {                                                       \
                float wj = wp[(tb << 3) + (S)];                     \
                a0 = fmaf(blo(Q.x), wj, a0);                        \
                a1 = fmaf(bhi(Q.x), wj, a1);                        \
                a2 = fmaf(blo(Q.y), wj, a2);                        \
                a3 = fmaf(bhi(Q.y), wj, a3);                        \
            }
            CONS(q0, 0) CONS(q1, 1) CONS(q2, 2) CONS(q3, 3)
            CONS(q4, 4) CONS(q5, 5) CONS(q6, 6) CONS(q7, 7)
#undef CONS
            __builtin_amdgcn_sched_barrier(0);
        }
        const float bo = bias[o];
        const int ol = (wv << 2) + oi;
        const int bl0 = 4 * lane;
        tile[bl0 + 0][ol] = a0 + bo;
        tile[bl0 + 1][ol] = a1 + bo;
        tile[bl0 + 2][ol] = a2 + bo;
        tile[bl0 + 3][ol] = a3 + bo;
    }
    __syncthreads();
    // coalesced store: 256 b x 16 o; 4 float4 per thread
    const int bl_ = t >> 2;         // 0..63
    const int ol4 = (t & 3) << 2;   // 0,4,8,12
#pragma unroll
    for (int r = 0; r < 4; ++r) {
        int bl = bl_ + (r << 6);
        vfloat4 v;
        v.x = tile[bl][ol4 + 0];
        v.y = tile[bl][ol4 + 1];
        v.z = tile[bl][ol4 + 2];
        v.w = tile[bl][ol4 + 3];
        __builtin_nontemporal_store(v,
            (vfloat4*)&out[(size_t)(bbase + bl) * O_ + obase + ol4]);
    }
}

// ---------------------------------------------------------------------------
// Fallback (only if workspace is unexpectedly small): correct but slow.
// ---------------------------------------------------------------------------
__global__ __launch_bounds__(256) void spl_naive(const float* __restrict__ x,
                                                 const int* __restrict__ idx,
                                                 const float* __restrict__ w,
                                                 const float* __restrict__ bias,
                                                 float* __restrict__ out) {
    int o = blockIdx.x * 256 + threadIdx.x;
    int b = blockIdx.y;
    const float* xr = x + (size_t)b * IN_;
    float acc = bias[o];
    for (int k = 0; k < K_; ++k)
        acc = fmaf(xr[idx[o * K_ + k]], w[o * K_ + k], acc);
    out[(size_t)b * O_ + o] = acc;
}

extern "C" void kernel_launch(void* const* d_in, const int* in_sizes, int n_in,
                              void* d_out, int out_size, void* d_ws, size_t ws_size,
                              hipStream_t stream) {
    const float* x    = (const float*)d_in[0];
    const int*   idx  = (const int*)d_in[1];
    const float* w    = (const float*)d_in[2];
    const float* bias = (const float*)d_in[3];
    float*       out  = (float*)d_out;

    const size_t xt_bytes = (size_t)IN_ * BP_ * sizeof(uint32_t);  // 32 MiB
    if (ws_size >= xt_bytes) {
        uint32_t* xT = (uint32_t*)d_ws;
        hipLaunchKernelGGL(xpose_pack, dim3(B_ / 64, IN_ / 64), dim3(256), 0, stream, x, xT);
        hipLaunchKernelGGL(spl_main, dim3((O_ / 16) * (B_ / 256)), dim3(256), 0, stream,
                           xT, idx, w, bias, out);
    } else {
        hipLaunchKernelGGL(spl_naive, dim3(O_ / 256, B_), dim3(256), 0, stream,
                           x, idx, w, bias, out);
    }
}

// Round 14
// 80.229 us; speedup vs baseline: 1.7351x; 1.0801x over previous
//
#include <hip/hip_runtime.h>
#include <cstdint>
#include <cstddef>

#define B_ 2048
#define IN_ 8192
#define O_ 4096
#define K_ 64
#define BP_ (B_ / 2)  // 1024 bf16-pair dwords per xT row

typedef float vfloat4 __attribute__((ext_vector_type(4)));  // clang-native for nt-store

// bf16 pair helpers: low 16 bits = even b, high 16 bits = odd b
__device__ __forceinline__ float blo(uint32_t p) { return __uint_as_float(p << 16); }
__device__ __forceinline__ float bhi(uint32_t p) { return __uint_as_float(p & 0xffff0000u); }

// ---------------------------------------------------------------------------
// Kernel 1: transpose + bf16-pack  x[B][IN] f32  ->  xT[IN][BP] u32 (bf16x2)
// ---------------------------------------------------------------------------
__global__ __launch_bounds__(256) void xpose_pack(const float* __restrict__ x,
                                                  uint32_t* __restrict__ xT) {
    __shared__ uint16_t T[64][65];  // 64 i x 64 b tile, +1 pad
    const int t  = threadIdx.x;
    const int b0 = blockIdx.x << 6;   // 32 tiles over B
    const int i0 = blockIdx.y << 6;   // 128 tiles over IN
    const int il = t & 63;
    const int bq = t >> 6;            // 0..3
#pragma unroll
    for (int r = 0; r < 16; ++r) {
        int bl = (bq << 4) + r;
        float v = x[(size_t)(b0 + bl) * IN_ + i0 + il];  // coalesced over il
        uint32_t u = __float_as_uint(v);
        u += 0x7fffu + ((u >> 16) & 1u);                  // round-to-nearest-even
        T[il][bl] = (uint16_t)(u >> 16);
    }
    __syncthreads();
#pragma unroll
    for (int r = 0; r < 8; ++r) {
        int flat = t + (r << 8);
        int iw = flat >> 5;   // 0..63
        int bp = flat & 31;   // 0..31
        uint32_t lo = T[iw][2 * bp];
        uint32_t hi = T[iw][2 * bp + 1];
        __builtin_nontemporal_store(lo | (hi << 16),
                                    &xT[(size_t)(i0 + iw) * BP_ + (b0 >> 1) + bp]);
    }
}

// ---------------------------------------------------------------------------
// Kernel 2: main (R9 structure — best measured: 66.5 us kernel, 80.2 total).
// Block = 256 threads = 4 waves. Block tile: 256 b x 16 o.
// XCD-aligned: b-tile = f&7 pins each 4 MB xT column slice to one XCD's L2.
// Lane-split dwordx4 gathers: one wave-load = TWO rows' 512B chunks
// (lanes 0-31 -> r0, lanes 32-63 -> r1, 16B/lane) = max request width.
// 8 gathers batched in registers, sched_barrier-pinned ahead of the FMAs.
// ---------------------------------------------------------------------------
__global__ __launch_bounds__(256, 4) void spl_main(const uint32_t* __restrict__ xT,
                                                   const int* __restrict__ idx,
                                                   const float* __restrict__ w,
                                                   const float* __restrict__ bias,
                                                   float* __restrict__ out) {
    __shared__ float tile[256][17];  // [b_local][o_local], 17.4 KB
    const int t     = threadIdx.x;
    const int lane  = t & 63;
    const int half  = lane >> 5;        // 0: even-slot rows, 1: odd-slot rows
    const int l5    = lane & 31;
    const int f     = blockIdx.x;
    const int btile = f & 7;            // == XCD id under round-robin dispatch
    const int otile = f >> 3;           // 0..255
    const int obase = otile << 4;
    const int bbase = btile << 8;
    const int cbase = bbase >> 1;       // chunk dword base (scalar)
    const int wv    = __builtin_amdgcn_readfirstlane(t >> 6);  // force scalar o

    for (int oi = 0; oi < 4; ++oi) {
        const int o = obase + (wv << 2) + oi;            // uniform per wave
        const int*   ip = idx + o * K_;                  // -> s_load
        const float* wp = w + o * K_;                    // -> s_load
        float a0 = 0.f, a1 = 0.f, a2 = 0.f, a3 = 0.f;
        float a4 = 0.f, a5 = 0.f, a6 = 0.f, a7 = 0.f;
#pragma unroll
        for (int kb = 0; kb < 4; ++kb) {
            // ---- issue 8 dwordx4 gathers covering 16 rows ----
            uint4 q[8];
            float ws[8];
#pragma unroll
            for (int j = 0; j < 8; ++j) {
                int k2 = (kb << 4) + 2 * j;
                int r0 = ip[k2];                         // wave-uniform (scalar)
                int r1 = ip[k2 + 1];
                const uint32_t* p0 = xT + ((size_t)r0 << 10) + cbase;
                const uint32_t* p1 = xT + ((size_t)r1 << 10) + cbase;
                const uint32_t* ps = half ? p1 : p0;     // v_cndmask on base
                q[j]  = *(const uint4*)(ps + (l5 << 2)); // 16B/lane, 1024B/wave
                ws[j] = half ? wp[k2 + 1] : wp[k2];
            }
            __builtin_amdgcn_sched_barrier(0);  // no FMA hoisted above the loads
            // ---- consume in issue order (progressive vmcnt drain) ----
#pragma unroll
            for (int j = 0; j < 8; ++j) {
                float wj = ws[j];
                a0 = fmaf(blo(q[j].x), wj, a0);
                a1 = fmaf(bhi(q[j].x), wj, a1);
                a2 = fmaf(blo(q[j].y), wj, a2);
                a3 = fmaf(bhi(q[j].y), wj, a3);
                a4 = fmaf(blo(q[j].z), wj, a4);
                a5 = fmaf(bhi(q[j].z), wj, a5);
                a6 = fmaf(blo(q[j].w), wj, a6);
                a7 = fmaf(bhi(q[j].w), wj, a7);
            }
        }
        // combine even-row half (lanes 0-31) with odd-row half (lanes 32-63);
        // lane l5 owns b = bbase + 8*l5 .. 8*l5+7
        const float bo = bias[o];
        const int ol = (wv << 2) + oi;
        float s0 = a0 + __shfl_xor(a0, 32, 64);
        float s1 = a1 + __shfl_xor(a1, 32, 64);
        float s2 = a2 + __shfl_xor(a2, 32, 64);
        float s3 = a3 + __shfl_xor(a3, 32, 64);
        float s4 = a4 + __shfl_xor(a4, 32, 64);
        float s5 = a5 + __shfl_xor(a5, 32, 64);
        float s6 = a6 + __shfl_xor(a6, 32, 64);
        float s7 = a7 + __shfl_xor(a7, 32, 64);
        if (half == 0) {
            const int bl0 = l5 << 3;
            tile[bl0 + 0][ol] = s0 + bo;
            tile[bl0 + 1][ol] = s1 + bo;
            tile[bl0 + 2][ol] = s2 + bo;
            tile[bl0 + 3][ol] = s3 + bo;
            tile[bl0 + 4][ol] = s4 + bo;
            tile[bl0 + 5][ol] = s5 + bo;
            tile[bl0 + 6][ol] = s6 + bo;
            tile[bl0 + 7][ol] = s7 + bo;
        }
    }
    __syncthreads();
    // coalesced store: 256 b x 16 o; 4 float4 per thread
    const int bl_ = t >> 2;         // 0..63
    const int ol4 = (t & 3) << 2;   // 0,4,8,12
#pragma unroll
    for (int r = 0; r < 4; ++r) {
        int bl = bl_ + (r << 6);
        vfloat4 v;
        v.x = tile[bl][ol4 + 0];
        v.y = tile[bl][ol4 + 1];
        v.z = tile[bl][ol4 + 2];
        v.w = tile[bl][ol4 + 3];
        __builtin_nontemporal_store(v,
            (vfloat4*)&out[(size_t)(bbase + bl) * O_ + obase + ol4]);
    }
}

// ---------------------------------------------------------------------------
// Fallback (only if workspace is unexpectedly small): correct but slow.
// ---------------------------------------------------------------------------
__global__ __launch_bounds__(256) void spl_naive(const float* __restrict__ x,
                                                 const int* __restrict__ idx,
                                                 const float* __restrict__ w,
                                                 const float* __restrict__ bias,
                                                 float* __restrict__ out) {
    int o = blockIdx.x * 256 + threadIdx.x;
    int b = blockIdx.y;
    const float* xr = x + (size_t)b * IN_;
    float acc = bias[o];
    for (int k = 0; k < K_; ++k)
        acc = fmaf(xr[idx[o * K_ + k]], w[o * K_ + k], acc);
    out[(size_t)b * O_ + o] = acc;
}

extern "C" void kernel_launch(void* const* d_in, const int* in_sizes, int n_in,
                              void* d_out, int out_size, void* d_ws, size_t ws_size,
                              hipStream_t stream) {
    const float* x    = (const float*)d_in[0];
    const int*   idx  = (const int*)d_in[1];
    const float* w    = (const float*)d_in[2];
    const float* bias = (const float*)d_in[3];
    float*       out  = (float*)d_out;

    const size_t xt_bytes = (size_t)IN_ * BP_ * sizeof(uint32_t);  // 32 MiB
    if (ws_size >= xt_bytes) {
        uint32_t* xT = (uint32_t*)d_ws;
        hipLaunchKernelGGL(xpose_pack, dim3(B_ / 64, IN_ / 64), dim3(256), 0, stream, x, xT);
        hipLaunchKernelGGL(spl_main, dim3((O_ / 16) * (B_ / 256)), dim3(256), 0, stream,
                           xT, idx, w, bias, out);
    } else {
        hipLaunchKernelGGL(spl_naive, dim3(O_ / 256, B_), dim3(256), 0, stream,
                           x, idx, w, bias, out);
    }
}